// Round 3
// baseline (6440.871 us; speedup 1.0000x reference)
//
#include <hip/hip_runtime.h>
#include <hip/hip_bf16.h>
#include <hip/hip_fp16.h>

#define HD 2
#define LAYERS 4
#define RELS 16
#define BASES 8

#define NB   512       // dst buckets (bucket = dst >> BSH)
#define BSH  11        // 2048 nodes per bucket
#define SBLK 512       // sort chunk blocks
#define TPB  256

// ============================ common ============================

// W[l][r][i][o] = sum_b comp[l,r,b] * V[l,b,i,o]; zero dot accumulator.
__global__ void prep_kernel(const float* __restrict__ V, const float* __restrict__ comp,
                            float* __restrict__ W, float* __restrict__ acc) {
    int idx = threadIdx.x;            // 0..255 = l*64 + r*4 + io
    if (idx < LAYERS * RELS * 4) {
        int l  = idx >> 6;
        int r  = (idx >> 2) & (RELS - 1);
        int io = idx & 3;
        float s = 0.f;
        for (int b = 0; b < BASES; ++b)
            s += comp[(l * RELS + r) * BASES + b] * V[(l * BASES + b) * 4 + io];
        W[idx] = s;
    }
    if (idx == 0) *acc = 0.f;
}

__global__ void finalize_kernel(const float* __restrict__ acc,
                                const float* __restrict__ b_mlp,
                                float* __restrict__ out) {
    float v = *acc + b_mlp[0];
    out[0] = 1.f / (1.f + expf(-v));
}

// features f32 -> half2 (4B/node): gather working set 4MB = one XCD L2.
__global__ __launch_bounds__(TPB) void f2h_kernel(const float2* __restrict__ f,
                                                  __half2* __restrict__ h, int N) {
    int i = blockIdx.x * TPB + threadIdx.x;
    int stride = gridDim.x * TPB;
    for (; i < N; i += stride)
        h[i] = __float22half2_rn(f[i]);
}

// ============================ sort path ============================

// S1: per-chunk histogram of dst buckets.  blockhist[blk*NB + bucket]
__global__ __launch_bounds__(TPB) void hist_kernel(const int* __restrict__ dst,
                                                   unsigned* __restrict__ blockhist,
                                                   int E, int per) {
    __shared__ unsigned hist[NB];
    for (int i = threadIdx.x; i < NB; i += TPB) hist[i] = 0u;
    __syncthreads();
    int blk = blockIdx.x;
    int e0 = blk * per;              // multiple of 4
    int e1 = min(e0 + per, E);
    const int4* dst4 = (const int4*)dst;
    int g0 = e0 >> 2, g1 = e1 >> 2;
    for (int g = g0 + threadIdx.x; g < g1; g += TPB) {
        int4 d = dst4[g];
        atomicAdd(&hist[((unsigned)d.x) >> BSH], 1u);
        atomicAdd(&hist[((unsigned)d.y) >> BSH], 1u);
        atomicAdd(&hist[((unsigned)d.z) >> BSH], 1u);
        atomicAdd(&hist[((unsigned)d.w) >> BSH], 1u);
    }
    for (int e = (g1 << 2) + threadIdx.x; e < e1; e += TPB)   // tail (E%4)
        atomicAdd(&hist[((unsigned)dst[e]) >> BSH], 1u);
    __syncthreads();
    for (int i = threadIdx.x; i < NB; i += TPB)
        blockhist[(size_t)blk * NB + i] = hist[i];
}

// S2a: per-bucket column exclusive scan over chunks (in place); totals[bucket] out.
__global__ __launch_bounds__(TPB) void colscan_kernel(unsigned* __restrict__ blockhist,
                                                      unsigned* __restrict__ totals) {
    int bucket = blockIdx.x;
    int t = threadIdx.x;
    unsigned v0 = blockhist[(size_t)(2 * t)     * NB + bucket];
    unsigned v1 = blockhist[(size_t)(2 * t + 1) * NB + bucket];
    unsigned run = v0 + v1;
    __shared__ unsigned s[TPB];
    s[t] = run;
    __syncthreads();
    for (int off = 1; off < TPB; off <<= 1) {
        unsigned x = (t >= off) ? s[t - off] : 0u;
        __syncthreads();
        s[t] += x;
        __syncthreads();
    }
    unsigned base = s[t] - run;
    blockhist[(size_t)(2 * t)     * NB + bucket] = base;
    blockhist[(size_t)(2 * t + 1) * NB + bucket] = base + v0;
    if (t == TPB - 1) totals[bucket] = s[TPB - 1];
}

// S2b: exclusive scan of NB totals -> base[NB+1].
__global__ __launch_bounds__(TPB) void scan_kernel(const unsigned* __restrict__ totals,
                                                   unsigned* __restrict__ base) {
    int t = threadIdx.x;
    unsigned v0 = totals[2 * t];
    unsigned v1 = totals[2 * t + 1];
    unsigned run = v0 + v1;
    __shared__ unsigned s[TPB];
    s[t] = run;
    __syncthreads();
    for (int off = 1; off < TPB; off <<= 1) {
        unsigned x = (t >= off) ? s[t - off] : 0u;
        __syncthreads();
        s[t] += x;
        __syncthreads();
    }
    unsigned b0 = s[t] - run;
    base[2 * t]     = b0;
    base[2 * t + 1] = b0 + v0;
    if (t == TPB - 1) base[NB] = s[TPB - 1];
}

// S3: scatter edges into dst-bucket order.
// packed: {src:u32,  doff[0:10] | typ[12:15] | f16(norm)[16:31]}
__global__ __launch_bounds__(TPB) void scatter_kernel(const int* __restrict__ src,
                                                      const int* __restrict__ dst,
                                                      const int* __restrict__ typ,
                                                      const float* __restrict__ norm,
                                                      const unsigned* __restrict__ blockhist,
                                                      const unsigned* __restrict__ base,
                                                      uint2* __restrict__ packed,
                                                      int E, int per) {
    __shared__ unsigned cnt[NB];
    int blk = blockIdx.x;
    for (int i = threadIdx.x; i < NB; i += TPB)
        cnt[i] = blockhist[(size_t)blk * NB + i] + base[i];
    __syncthreads();
    int e0 = blk * per;
    int e1 = min(e0 + per, E);
    const int4*   src4 = (const int4*)src;
    const int4*   dst4 = (const int4*)dst;
    const int4*   typ4 = (const int4*)typ;
    const float4* nrm4 = (const float4*)norm;
    int g0 = e0 >> 2, g1 = e1 >> 2;

#define PUT(SS, DD, TT, NN)                                                       \
    {                                                                             \
        unsigned _d = (unsigned)(DD);                                             \
        unsigned _bucket = _d >> BSH;                                             \
        unsigned _pos = atomicAdd(&cnt[_bucket], 1u);                             \
        unsigned _w1 = (_d & ((1u << BSH) - 1u)) | (((unsigned)(TT)) << 12) |     \
                       ((unsigned)__half_as_ushort(__float2half_rn(NN)) << 16);   \
        packed[_pos] = make_uint2((unsigned)(SS), _w1);                           \
    }

    for (int g = g0 + threadIdx.x; g < g1; g += TPB) {
        int4 s = src4[g];
        int4 d = dst4[g];
        int4 t = typ4[g];
        float4 nm = nrm4[g];
        PUT(s.x, d.x, t.x, nm.x)
        PUT(s.y, d.y, t.y, nm.y)
        PUT(s.z, d.z, t.z, nm.z)
        PUT(s.w, d.w, t.w, nm.w)
    }
    for (int e = (g1 << 2) + threadIdx.x; e < e1; e += TPB)   // tail (E%4)
        PUT(src[e], dst[e], typ[e], norm[e])
#undef PUT
}

// S4: within-bucket counting sort -> exact dst order + CSR offsets.
// One block per bucket (~31K edges, 250KB region: L2-resident, so the
// scattered rec[] writes are absorbed by L2 and written back as full lines).
// rec: {src:u32, typ[0:3] | f16(norm)[4:19]}
__global__ __launch_bounds__(TPB) void subsort_kernel(
    const uint2* __restrict__ packed,
    const unsigned* __restrict__ base,
    uint2* __restrict__ rec,
    unsigned* __restrict__ off,
    int N, int E)
{
    __shared__ unsigned hist[1 << BSH];   // 8KB: counts, then global cursors
    __shared__ unsigned wpart[TPB / 64];
    int b = blockIdx.x;
    int t = threadIdx.x;
    unsigned e0 = base[b], e1 = base[b + 1];

    for (int i = t; i < (1 << BSH); i += TPB) hist[i] = 0u;
    __syncthreads();

    // pass 1: per-node histogram
    for (unsigned e = e0 + t; e < e1; e += TPB)
        atomicAdd(&hist[packed[e].y & ((1u << BSH) - 1u)], 1u);
    __syncthreads();

    // exclusive scan of 2048 bins: 8 serial bins/thread + block scan
    unsigned loc[8];
    unsigned run = 0;
#pragma unroll
    for (int k = 0; k < 8; ++k) { loc[k] = run; run += hist[t * 8 + k]; }

    unsigned lane = t & 63, wv = t >> 6;
    unsigned v = run;
    for (int o = 1; o < 64; o <<= 1) {
        unsigned u = __shfl_up(v, o, 64);
        if (lane >= o) v += u;
    }
    if (lane == 63) wpart[wv] = v;
    __syncthreads();
    unsigned wbase = 0;
    for (int w = 0; w < (int)(TPB / 64); ++w) if (w < (int)wv) wbase += wpart[w];
    unsigned excl = wbase + v - run;     // exclusive prefix of this thread's 1st bin
    __syncthreads();                     // everyone done reading hist as counts

    unsigned nodeBase = (unsigned)b << BSH;
#pragma unroll
    for (int k = 0; k < 8; ++k) {
        unsigned p = e0 + excl + loc[k];
        unsigned node = nodeBase + (unsigned)(t * 8 + k);
        hist[t * 8 + k] = p;             // global cursor for this node's segment
        if (node < (unsigned)N) off[node] = p;
    }
    if (b == (int)gridDim.x - 1 && t == 0) off[N] = (unsigned)E;
    __syncthreads();

    // pass 2: scatter into exact order (writes land in L2-resident region)
    for (unsigned e = e0 + t; e < e1; e += TPB) {
        uint2 q = packed[e];
        unsigned dof = q.y & ((1u << BSH) - 1u);
        unsigned pos = atomicAdd(&hist[dof], 1u);
        rec[pos] = make_uint2(q.x, q.y >> 12);
    }
}

// Per-layer edge pass over CSR: one thread per dst node, register
// accumulation, ZERO atomics, no LDS accumulator. Fused epilogue.
__global__ __launch_bounds__(TPB) void csr_edge_kernel(
    const uint2* __restrict__ rec,       // exact dst order
    const unsigned* __restrict__ off,    // [N+1]
    const __half2* __restrict__ xh,      // gather source [N], 4MB
    const float* __restrict__ Wl,        // [64] this layer
    const float* __restrict__ bias2,     // [2]
    const __half2* __restrict__ skiph,   // nullable
    __half2* __restrict__ outh,          // nullable
    const float2* __restrict__ w2,       // nullable (w_mlp as float2[N], f32)
    float* __restrict__ acc,             // dot accumulator
    int N, int do_relu)
{
    __shared__ float sW[64];
    __shared__ float wred[TPB / 64];
    int t = threadIdx.x;
    if (t < 64) sW[t] = Wl[t];
    __syncthreads();

    int d = blockIdx.x * TPB + t;
    float r0 = 0.f, r1 = 0.f;
    const unsigned long long* rec8 = (const unsigned long long*)rec;
    if (d < N) {
        unsigned e0 = off[d], e1 = off[d + 1];
        for (unsigned e = e0; e < e1; ++e) {
            unsigned long long q = __builtin_nontemporal_load(&rec8[e]);
            unsigned s = (unsigned)(q & 0xffffffffu);
            unsigned m = (unsigned)(q >> 32);
            __half2 hv = xh[s];
            float x0 = __low2float(hv), x1 = __high2float(hv);
            int wb = (int)(m & 15u) << 2;
            float nm = __half2float(__ushort_as_half((unsigned short)((m >> 4) & 0xffffu)));
            r0 += (x0 * sW[wb + 0] + x1 * sW[wb + 2]) * nm;
            r1 += (x0 * sW[wb + 1] + x1 * sW[wb + 3]) * nm;
        }
        r0 += bias2[0]; r1 += bias2[1];
        if (do_relu) { r0 = fmaxf(r0, 0.f); r1 = fmaxf(r1, 0.f); }
        if (skiph) { __half2 sv = skiph[d]; r0 += __low2float(sv); r1 += __high2float(sv); }
        if (outh) outh[d] = __float22half2_rn(make_float2(r0, r1));
    }
    if (w2) {
        float part = 0.f;
        if (d < N) { float2 wv = w2[d]; part = r0 * wv.x + r1 * wv.y; }
        for (int o = 32; o > 0; o >>= 1) part += __shfl_down(part, o, 64);
        if ((t & 63) == 0) wred[t >> 6] = part;
        __syncthreads();
        if (t == 0) {
            float s = 0.f;
            for (int w = 0; w < (int)(TPB / 64); ++w) s += wred[w];
            atomicAdd(acc, s);
        }
    }
}

// ============================ fallback path (round-1, known-good) ============================

__global__ void zero_kernel(float4* __restrict__ p, int n4) {
    int i = blockIdx.x * blockDim.x + threadIdx.x;
    int stride = gridDim.x * blockDim.x;
    for (; i < n4; i += stride) p[i] = make_float4(0.f, 0.f, 0.f, 0.f);
}

__global__ __launch_bounds__(256) void edge_kernel(
    const float* __restrict__ x, const int* __restrict__ src,
    const int* __restrict__ dst, const int* __restrict__ typ,
    const float* __restrict__ norm, const float* __restrict__ Wl,
    float* __restrict__ h, int E)
{
    __shared__ float sW[64];
    if (threadIdx.x < 64) sW[threadIdx.x] = Wl[threadIdx.x];
    __syncthreads();
    const float2* __restrict__ x2 = (const float2*)x;
    int tid = blockIdx.x * blockDim.x + threadIdx.x;
    int stride = gridDim.x * blockDim.x;
    for (int e = tid; e < E; e += stride) {
        int s = src[e], d = dst[e], t = typ[e];
        float nm = norm[e];
        float2 xv = x2[s];
        int wb = t << 2;
        float m0 = (xv.x * sW[wb + 0] + xv.y * sW[wb + 2]) * nm;
        float m1 = (xv.x * sW[wb + 1] + xv.y * sW[wb + 3]) * nm;
        atomicAdd(&h[2 * (size_t)d],     m0);
        atomicAdd(&h[2 * (size_t)d + 1], m1);
    }
}

__global__ void node_kernel(const float* __restrict__ h, const float* __restrict__ bias_l,
                            const float* __restrict__ skip, float* __restrict__ xout,
                            int N, int do_relu)
{
    float b0 = bias_l[0], b1 = bias_l[1];
    const float2* __restrict__ h2 = (const float2*)h;
    const float2* __restrict__ s2 = (const float2*)skip;
    float2* __restrict__ o2 = (float2*)xout;
    int i = blockIdx.x * blockDim.x + threadIdx.x;
    int stride = gridDim.x * blockDim.x;
    for (; i < N; i += stride) {
        float2 v = h2[i];
        v.x += b0; v.y += b1;
        if (do_relu) { v.x = fmaxf(v.x, 0.f); v.y = fmaxf(v.y, 0.f); }
        if (skip) { float2 sv = s2[i]; v.x += sv.x; v.y += sv.y; }
        o2[i] = v;
    }
}

__global__ __launch_bounds__(256) void dot_kernel(const float* __restrict__ a,
                                                  const float* __restrict__ b,
                                                  float* __restrict__ acc, int n)
{
    int i = blockIdx.x * blockDim.x + threadIdx.x;
    int stride = gridDim.x * blockDim.x;
    float s = 0.f;
    int n4 = n >> 2;
    const float4* __restrict__ a4 = (const float4*)a;
    const float4* __restrict__ b4 = (const float4*)b;
    for (int g = i; g < n4; g += stride) {
        float4 av = a4[g], bv = b4[g];
        s += av.x * bv.x + av.y * bv.y + av.z * bv.z + av.w * bv.w;
    }
    for (int e = (n4 << 2) + i; e < n; e += stride) s += a[e] * b[e];
    for (int off = 32; off > 0; off >>= 1) s += __shfl_down(s, off, 64);
    __shared__ float wsum[4];
    int lane = threadIdx.x & 63, wv = threadIdx.x >> 6;
    if (lane == 0) wsum[wv] = s;
    __syncthreads();
    if (threadIdx.x == 0) atomicAdd(acc, wsum[0] + wsum[1] + wsum[2] + wsum[3]);
}

// ============================ launch ============================

static inline size_t align256(size_t x) { return (x + 255) & ~(size_t)255; }

extern "C" void kernel_launch(void* const* d_in, const int* in_sizes, int n_in,
                              void* d_out, int out_size, void* d_ws, size_t ws_size,
                              hipStream_t stream) {
    const float* features = (const float*)d_in[0];   // [N*2]
    const float* norm     = (const float*)d_in[1];   // [E]
    const float* V        = (const float*)d_in[2];   // [L,B,2,2]
    const float* comp     = (const float*)d_in[3];   // [L,R,B]
    const float* bias     = (const float*)d_in[4];   // [L,2]
    const float* w_mlp    = (const float*)d_in[5];   // [N*2]
    const float* b_mlp    = (const float*)d_in[6];   // [1]
    const int*   esrc     = (const int*)d_in[7];
    const int*   edst     = (const int*)d_in[8];
    const int*   etyp     = (const int*)d_in[9];

    int NH = in_sizes[0];
    int N  = NH / 2;
    int E  = in_sizes[7];

    char* ws = (char*)d_ws;
    size_t oW    = 0;                                        // [256] f32
    size_t oAcc  = align256(oW + 1024);
    size_t oBase = align256(oAcc + 4);
    size_t oTot  = align256(oBase + (size_t)(NB + 1) * 4);
    size_t oFH   = align256(oTot + (size_t)NB * 4);          // half2 features [N]
    size_t oAH   = align256(oFH + (size_t)N * 4);
    size_t oBH   = align256(oAH + (size_t)N * 4);
    size_t oCH   = align256(oBH + (size_t)N * 4);
    size_t oOff  = align256(oCH + (size_t)N * 4);            // u32 [N+1]
    size_t oHist = align256(oOff + (size_t)(N + 1) * 4);     // u32 [SBLK*NB]
    size_t oPack = align256(oHist + (size_t)SBLK * NB * 4);  // uint2 [E]
    size_t oRec  = align256(oPack + (size_t)E * 8);          // uint2 [E]
    size_t REQ   = oRec + (size_t)E * 8;

    // fallback f32 scratch overlays the sort-path big arrays
    float* A = (float*)(ws + oFH);
    float* B = (float*)(ws + align256(oFH + (size_t)NH * 4));
    float* C = (float*)(ws + align256(oFH + 2 * align256((size_t)NH * 4)));

    float* W   = (float*)(ws + oW);
    float* acc = (float*)(ws + oAcc);

    prep_kernel<<<1, 256, 0, stream>>>(V, comp, W, acc);

    if (ws_size >= REQ && N <= (1 << 20)) {
        __half2* FH = (__half2*)(ws + oFH);
        __half2* AH = (__half2*)(ws + oAH);
        __half2* BH = (__half2*)(ws + oBH);
        __half2* CH = (__half2*)(ws + oCH);
        unsigned* base      = (unsigned*)(ws + oBase);
        unsigned* totals    = (unsigned*)(ws + oTot);
        unsigned* offArr    = (unsigned*)(ws + oOff);
        unsigned* blockhist = (unsigned*)(ws + oHist);
        uint2*    packed    = (uint2*)(ws + oPack);
        uint2*    rec       = (uint2*)(ws + oRec);

        int per = (((E + SBLK - 1) / SBLK) + 3) & ~3;   // multiple of 4
        int nbkt = (N + (1 << BSH) - 1) >> BSH;

        int cb = min((N + TPB - 1) / TPB, 2048);
        f2h_kernel    <<<cb,   TPB, 0, stream>>>((const float2*)features, FH, N);
        hist_kernel   <<<SBLK, TPB, 0, stream>>>(edst, blockhist, E, per);
        colscan_kernel<<<NB,   TPB, 0, stream>>>(blockhist, totals);
        scan_kernel   <<<1,    TPB, 0, stream>>>(totals, base);
        scatter_kernel<<<SBLK, TPB, 0, stream>>>(esrc, edst, etyp, norm,
                                                 blockhist, base, packed, E, per);
        subsort_kernel<<<nbkt, TPB, 0, stream>>>(packed, base, rec, offArr, N, E);

        int ngrid = (N + TPB - 1) / TPB;
        const float2* w2 = (const float2*)w_mlp;

        // L0: AH = relu(h0 + b0)
        csr_edge_kernel<<<ngrid, TPB, 0, stream>>>(rec, offArr, FH, W + 0,
            bias + 0, nullptr, AH, nullptr, acc, N, 1);
        // L1: BH = relu(h1 + b1) + features
        csr_edge_kernel<<<ngrid, TPB, 0, stream>>>(rec, offArr, AH, W + 64,
            bias + 2, FH, BH, nullptr, acc, N, 1);
        // L2: CH = relu(h2 + b2)
        csr_edge_kernel<<<ngrid, TPB, 0, stream>>>(rec, offArr, BH, W + 128,
            bias + 4, nullptr, CH, nullptr, acc, N, 1);
        // L3: x4 = (h3 + b3) + B, fused dot with w_mlp (x4 not stored)
        csr_edge_kernel<<<ngrid, TPB, 0, stream>>>(rec, offArr, CH, W + 192,
            bias + 6, BH, nullptr, w2, acc, N, 0);
    } else {
        // fallback: round-1 atomic path (f32 throughout)
        int zb = (NH / 4 + 255) / 256;
        int eb = (E / 4 + 255) / 256;
        int nb = (N + 255) / 256;
        int db = (NH / 4 + 255) / 256;

        zero_kernel<<<zb, 256, 0, stream>>>((float4*)A, NH / 4);
        edge_kernel<<<eb, 256, 0, stream>>>(features, esrc, edst, etyp, norm, W + 0, A, E);
        node_kernel<<<nb, 256, 0, stream>>>(A, bias + 0, nullptr, A, N, 1);

        zero_kernel<<<zb, 256, 0, stream>>>((float4*)B, NH / 4);
        edge_kernel<<<eb, 256, 0, stream>>>(A, esrc, edst, etyp, norm, W + 64, B, E);
        node_kernel<<<nb, 256, 0, stream>>>(B, bias + 2, features, B, N, 1);

        zero_kernel<<<zb, 256, 0, stream>>>((float4*)C, NH / 4);
        edge_kernel<<<eb, 256, 0, stream>>>(B, esrc, edst, etyp, norm, W + 128, C, E);
        node_kernel<<<nb, 256, 0, stream>>>(C, bias + 4, nullptr, C, N, 1);

        zero_kernel<<<zb, 256, 0, stream>>>((float4*)A, NH / 4);
        edge_kernel<<<eb, 256, 0, stream>>>(C, esrc, edst, etyp, norm, W + 192, A, E);
        node_kernel<<<nb, 256, 0, stream>>>(A, bias + 6, B, A, N, 0);

        dot_kernel<<<db, 256, 0, stream>>>(A, w_mlp, acc, NH);
    }

    finalize_kernel<<<1, 1, 0, stream>>>(acc, b_mlp, (float*)d_out);
}

// Round 4
// 1991.458 us; speedup vs baseline: 3.2342x; 3.2342x over previous
//
#include <hip/hip_runtime.h>
#include <hip/hip_bf16.h>
#include <hip/hip_fp16.h>

#define HD 2
#define LAYERS 4
#define RELS 16
#define BASES 8

#define BSH   10            // 1024 nodes per bucket (bucket fits in LDS for subsort)
#define NB    1024          // dst buckets (bucket = dst >> BSH); N<=2^20
#define NBINS (1 << BSH)    // nodes per bucket
#define SBLK  512           // sort chunk blocks
#define TPB   256
#define CAP   18176         // max staged edges per bucket (mean ~16.4K, +14 sigma)
#define OVFCAP 40960        // overflow slot capacity (edges)

static const int SUBSORT_LDS_BYTES = CAP * 8 + NBINS * 4 + 64;   // ~146 KB

// ============================ common ============================

// W[l][r][i][o] = sum_b comp[l,r,b] * V[l,b,i,o]; zero accumulators.
__global__ void prep_kernel(const float* __restrict__ V, const float* __restrict__ comp,
                            float* __restrict__ W, float* __restrict__ acc,
                            unsigned* __restrict__ ovfctr) {
    int idx = threadIdx.x;            // 0..255 = l*64 + r*4 + io
    if (idx < LAYERS * RELS * 4) {
        int l  = idx >> 6;
        int r  = (idx >> 2) & (RELS - 1);
        int io = idx & 3;
        float s = 0.f;
        for (int b = 0; b < BASES; ++b)
            s += comp[(l * RELS + r) * BASES + b] * V[(l * BASES + b) * 4 + io];
        W[idx] = s;
    }
    if (idx == 0) { *acc = 0.f; *ovfctr = 0u; }
}

__global__ void finalize_kernel(const float* __restrict__ acc,
                                const float* __restrict__ b_mlp,
                                float* __restrict__ out) {
    float v = *acc + b_mlp[0];
    out[0] = 1.f / (1.f + expf(-v));
}

// features f32 -> half2 (4B/node): gather working set 4MB = one XCD L2.
__global__ __launch_bounds__(TPB) void f2h_kernel(const float2* __restrict__ f,
                                                  __half2* __restrict__ h, int N) {
    int i = blockIdx.x * TPB + threadIdx.x;
    int stride = gridDim.x * TPB;
    for (; i < N; i += stride)
        h[i] = __float22half2_rn(f[i]);
}

// ============================ sort path ============================

// S1: per-chunk histogram of dst buckets.  blockhist[blk*NB + bucket]
__global__ __launch_bounds__(TPB) void hist_kernel(const int* __restrict__ dst,
                                                   unsigned* __restrict__ blockhist,
                                                   int E, int per) {
    __shared__ unsigned hist[NB];
    for (int i = threadIdx.x; i < NB; i += TPB) hist[i] = 0u;
    __syncthreads();
    int blk = blockIdx.x;
    int e0 = blk * per;              // multiple of 4
    int e1 = min(e0 + per, E);
    const int4* dst4 = (const int4*)dst;
    int g0 = e0 >> 2, g1 = e1 >> 2;
    for (int g = g0 + threadIdx.x; g < g1; g += TPB) {
        int4 d = dst4[g];
        atomicAdd(&hist[((unsigned)d.x) >> BSH], 1u);
        atomicAdd(&hist[((unsigned)d.y) >> BSH], 1u);
        atomicAdd(&hist[((unsigned)d.z) >> BSH], 1u);
        atomicAdd(&hist[((unsigned)d.w) >> BSH], 1u);
    }
    for (int e = (g1 << 2) + threadIdx.x; e < e1; e += TPB)   // tail (E%4)
        atomicAdd(&hist[((unsigned)dst[e]) >> BSH], 1u);
    __syncthreads();
    for (int i = threadIdx.x; i < NB; i += TPB)
        blockhist[(size_t)blk * NB + i] = hist[i];
}

// S2a: per-bucket column exclusive scan over chunks (in place); totals[bucket] out.
// SBLK/TPB = 2 chunks per thread.
__global__ __launch_bounds__(TPB) void colscan_kernel(unsigned* __restrict__ blockhist,
                                                      unsigned* __restrict__ totals) {
    int bucket = blockIdx.x;
    int t = threadIdx.x;
    unsigned v0 = blockhist[(size_t)(2 * t)     * NB + bucket];
    unsigned v1 = blockhist[(size_t)(2 * t + 1) * NB + bucket];
    unsigned run = v0 + v1;
    __shared__ unsigned s[TPB];
    s[t] = run;
    __syncthreads();
    for (int off = 1; off < TPB; off <<= 1) {
        unsigned x = (t >= off) ? s[t - off] : 0u;
        __syncthreads();
        s[t] += x;
        __syncthreads();
    }
    unsigned base = s[t] - run;
    blockhist[(size_t)(2 * t)     * NB + bucket] = base;
    blockhist[(size_t)(2 * t + 1) * NB + bucket] = base + v0;
    if (t == TPB - 1) totals[bucket] = s[TPB - 1];
}

// S2b: exclusive scan of NB totals -> base[NB+1].  NB/TPB = 4 per thread.
__global__ __launch_bounds__(TPB) void scan_kernel(const unsigned* __restrict__ totals,
                                                   unsigned* __restrict__ base) {
    int t = threadIdx.x;
    unsigned v[4]; unsigned run = 0;
#pragma unroll
    for (int k = 0; k < 4; ++k) { v[k] = run; run += totals[4 * t + k]; }
    __shared__ unsigned s[TPB];
    s[t] = run;
    __syncthreads();
    for (int off = 1; off < TPB; off <<= 1) {
        unsigned x = (t >= off) ? s[t - off] : 0u;
        __syncthreads();
        s[t] += x;
        __syncthreads();
    }
    unsigned b0 = s[t] - run;
#pragma unroll
    for (int k = 0; k < 4; ++k) base[4 * t + k] = b0 + v[k];
    if (t == TPB - 1) base[NB] = s[TPB - 1];
}

// S3: scatter edges into dst-bucket order.
// packed: {src:u32,  doff[0:9] | typ[12:15] | f16(norm)[16:31]}
__global__ __launch_bounds__(TPB) void scatter_kernel(const int* __restrict__ src,
                                                      const int* __restrict__ dst,
                                                      const int* __restrict__ typ,
                                                      const float* __restrict__ norm,
                                                      const unsigned* __restrict__ blockhist,
                                                      const unsigned* __restrict__ base,
                                                      uint2* __restrict__ packed,
                                                      int E, int per) {
    __shared__ unsigned cnt[NB];
    int blk = blockIdx.x;
    for (int i = threadIdx.x; i < NB; i += TPB)
        cnt[i] = blockhist[(size_t)blk * NB + i] + base[i];
    __syncthreads();
    int e0 = blk * per;
    int e1 = min(e0 + per, E);
    const int4*   src4 = (const int4*)src;
    const int4*   dst4 = (const int4*)dst;
    const int4*   typ4 = (const int4*)typ;
    const float4* nrm4 = (const float4*)norm;
    int g0 = e0 >> 2, g1 = e1 >> 2;

#define PUT(SS, DD, TT, NN)                                                       \
    {                                                                             \
        unsigned _d = (unsigned)(DD);                                             \
        unsigned _bucket = _d >> BSH;                                             \
        unsigned _pos = atomicAdd(&cnt[_bucket], 1u);                             \
        unsigned _w1 = (_d & ((1u << BSH) - 1u)) | (((unsigned)(TT)) << 12) |     \
                       ((unsigned)__half_as_ushort(__float2half_rn(NN)) << 16);   \
        packed[_pos] = make_uint2((unsigned)(SS), _w1);                           \
    }

    for (int g = g0 + threadIdx.x; g < g1; g += TPB) {
        int4 s = src4[g];
        int4 d = dst4[g];
        int4 t = typ4[g];
        float4 nm = nrm4[g];
        PUT(s.x, d.x, t.x, nm.x)
        PUT(s.y, d.y, t.y, nm.y)
        PUT(s.z, d.z, t.z, nm.z)
        PUT(s.w, d.w, t.w, nm.w)
    }
    for (int e = (g1 << 2) + threadIdx.x; e < e1; e += TPB)   // tail (E%4)
        PUT(src[e], dst[e], typ[e], norm[e])
#undef PUT
}

// S4: IN-PLACE within-bucket counting sort -> exact dst order + CSR offsets.
// One block per bucket. The entire bucket (~16.4K edges, 131KB) is staged in
// dynamic LDS (reads complete before writes -> in-place is race-free), then
// scattered back into the same packed[] range in exact dst order.
// Overflow (>CAP edges, +14 sigma, ~impossible) stages via a global scratch slot.
__global__ __launch_bounds__(TPB) void subsort_kernel(
    unsigned long long* __restrict__ packed8,     // sorted in place
    const unsigned* __restrict__ base,
    unsigned* __restrict__ off,                   // [N+1]
    unsigned long long* __restrict__ ovfbuf,      // 2MB scratch (dead blockhist)
    unsigned* __restrict__ ovfctr,
    int N, int E)
{
    extern __shared__ unsigned long long smem[];
    unsigned long long* stage = smem;                       // CAP entries
    unsigned* hist  = (unsigned*)(smem + CAP);              // NBINS counts->cursors
    unsigned* wpart = hist + NBINS;                         // per-wave scan partials

    int b = blockIdx.x;
    int t = threadIdx.x;
    unsigned e0 = base[b], e1 = base[b + 1];
    unsigned len = e1 - e0;

    __shared__ unsigned long long* gs;
    if (len > CAP) {                  // statistical impossibility; safe anyway
        if (t == 0) {
            unsigned slot = atomicAdd(ovfctr, 1u) % 6u;
            gs = ovfbuf + (size_t)slot * OVFCAP;
        }
        __syncthreads();
        stage = gs;
    }

    for (int i = t; i < NBINS; i += TPB) hist[i] = 0u;
    __syncthreads();

    // pass 1: stage bucket + per-node histogram
    for (unsigned i = t; i < len; i += TPB) {
        unsigned long long q = packed8[e0 + i];
        stage[i] = q;
        atomicAdd(&hist[(unsigned)(q >> 32) & (NBINS - 1u)], 1u);
    }
    __syncthreads();

    // exclusive scan of NBINS bins: 4 serial bins/thread + wave/block scan
    unsigned loc[4]; unsigned run = 0;
#pragma unroll
    for (int k = 0; k < 4; ++k) { loc[k] = run; run += hist[t * 4 + k]; }

    unsigned lane = t & 63, wv = t >> 6;
    unsigned v = run;
    for (int o = 1; o < 64; o <<= 1) {
        unsigned u = __shfl_up(v, o, 64);
        if (lane >= (unsigned)o) v += u;
    }
    if (lane == 63) wpart[wv] = v;
    __syncthreads();                 // also: all hist reads done
    unsigned wbase = 0;
    for (int w = 0; w < (int)(TPB / 64); ++w) if ((unsigned)w < wv) wbase += wpart[w];
    unsigned excl = wbase + v - run; // exclusive prefix of this thread's 1st bin

    unsigned nodeBase = (unsigned)b << BSH;
#pragma unroll
    for (int k = 0; k < 4; ++k) {
        unsigned bin = (unsigned)(t * 4 + k);
        unsigned pos = e0 + excl + loc[k];
        hist[bin] = pos;             // global cursor for this node's segment
        unsigned node = nodeBase + bin;
        if (node < (unsigned)N) off[node] = pos;
    }
    if (b == 0 && t == 0) off[N] = (unsigned)E;
    __syncthreads();

    // pass 2: scatter back into exact dst order (within own [e0,e1) range)
    for (unsigned i = t; i < len; i += TPB) {
        unsigned long long q = stage[i];
        unsigned bin = (unsigned)(q >> 32) & (NBINS - 1u);
        unsigned pos = atomicAdd(&hist[bin], 1u);
        packed8[pos] = q;
    }
}

// Per-layer edge pass over CSR: one thread per dst node, register
// accumulation, ZERO atomics, no LDS accumulator. Fused epilogue.
__global__ __launch_bounds__(TPB) void csr_edge_kernel(
    const unsigned long long* __restrict__ rec8,  // packed, exact dst order
    const unsigned* __restrict__ off,             // [N+1]
    const __half2* __restrict__ xh,               // gather source [N], 4MB
    const float* __restrict__ Wl,                 // [64] this layer
    const float* __restrict__ bias2,              // [2]
    const __half2* __restrict__ skiph,            // nullable
    __half2* __restrict__ outh,                   // nullable
    const float2* __restrict__ w2,                // nullable (w_mlp as float2[N])
    float* __restrict__ acc,                      // dot accumulator
    int N, int do_relu)
{
    __shared__ float sW[64];
    __shared__ float wred[TPB / 64];
    int t = threadIdx.x;
    if (t < 64) sW[t] = Wl[t];
    __syncthreads();

    int d = blockIdx.x * TPB + t;
    float r0 = 0.f, r1 = 0.f;
    if (d < N) {
        unsigned e = off[d], e1 = off[d + 1];
        for (; e < e1; ++e) {
            unsigned long long q = __builtin_nontemporal_load(&rec8[e]);
            __half2 hv = xh[(unsigned)q];                  // low 32 bits = src
            unsigned m = (unsigned)(q >> 32);
            float x0 = __low2float(hv), x1 = __high2float(hv);
            int wb = (int)((m >> 12) & 15u) << 2;
            float nm = __half2float(__ushort_as_half((unsigned short)(m >> 16)));
            r0 += (x0 * sW[wb + 0] + x1 * sW[wb + 2]) * nm;
            r1 += (x0 * sW[wb + 1] + x1 * sW[wb + 3]) * nm;
        }
        r0 += bias2[0]; r1 += bias2[1];
        if (do_relu) { r0 = fmaxf(r0, 0.f); r1 = fmaxf(r1, 0.f); }
        if (skiph) { __half2 sv = skiph[d]; r0 += __low2float(sv); r1 += __high2float(sv); }
        if (outh) outh[d] = __float22half2_rn(make_float2(r0, r1));
    }
    if (w2) {
        float part = 0.f;
        if (d < N) { float2 wv = w2[d]; part = r0 * wv.x + r1 * wv.y; }
        for (int o = 32; o > 0; o >>= 1) part += __shfl_down(part, o, 64);
        if ((t & 63) == 0) wred[t >> 6] = part;
        __syncthreads();
        if (t == 0) {
            float s = 0.f;
            for (int w = 0; w < (int)(TPB / 64); ++w) s += wred[w];
            atomicAdd(acc, s);
        }
    }
}

// ============================ fallback path (round-1, known-good) ============================

__global__ void zero_kernel(float4* __restrict__ p, int n4) {
    int i = blockIdx.x * blockDim.x + threadIdx.x;
    int stride = gridDim.x * blockDim.x;
    for (; i < n4; i += stride) p[i] = make_float4(0.f, 0.f, 0.f, 0.f);
}

__global__ __launch_bounds__(256) void edge_kernel(
    const float* __restrict__ x, const int* __restrict__ src,
    const int* __restrict__ dst, const int* __restrict__ typ,
    const float* __restrict__ norm, const float* __restrict__ Wl,
    float* __restrict__ h, int E)
{
    __shared__ float sW[64];
    if (threadIdx.x < 64) sW[threadIdx.x] = Wl[threadIdx.x];
    __syncthreads();
    const float2* __restrict__ x2 = (const float2*)x;
    int tid = blockIdx.x * blockDim.x + threadIdx.x;
    int stride = gridDim.x * blockDim.x;
    for (int e = tid; e < E; e += stride) {
        int s = src[e], d = dst[e], t = typ[e];
        float nm = norm[e];
        float2 xv = x2[s];
        int wb = t << 2;
        float m0 = (xv.x * sW[wb + 0] + xv.y * sW[wb + 2]) * nm;
        float m1 = (xv.x * sW[wb + 1] + xv.y * sW[wb + 3]) * nm;
        atomicAdd(&h[2 * (size_t)d],     m0);
        atomicAdd(&h[2 * (size_t)d + 1], m1);
    }
}

__global__ void node_kernel(const float* __restrict__ h, const float* __restrict__ bias_l,
                            const float* __restrict__ skip, float* __restrict__ xout,
                            int N, int do_relu)
{
    float b0 = bias_l[0], b1 = bias_l[1];
    const float2* __restrict__ h2 = (const float2*)h;
    const float2* __restrict__ s2 = (const float2*)skip;
    float2* __restrict__ o2 = (float2*)xout;
    int i = blockIdx.x * blockDim.x + threadIdx.x;
    int stride = gridDim.x * blockDim.x;
    for (; i < N; i += stride) {
        float2 v = h2[i];
        v.x += b0; v.y += b1;
        if (do_relu) { v.x = fmaxf(v.x, 0.f); v.y = fmaxf(v.y, 0.f); }
        if (skip) { float2 sv = s2[i]; v.x += sv.x; v.y += sv.y; }
        o2[i] = v;
    }
}

__global__ __launch_bounds__(256) void dot_kernel(const float* __restrict__ a,
                                                  const float* __restrict__ b,
                                                  float* __restrict__ acc, int n)
{
    int i = blockIdx.x * blockDim.x + threadIdx.x;
    int stride = gridDim.x * blockDim.x;
    float s = 0.f;
    int n4 = n >> 2;
    const float4* __restrict__ a4 = (const float4*)a;
    const float4* __restrict__ b4 = (const float4*)b;
    for (int g = i; g < n4; g += stride) {
        float4 av = a4[g], bv = b4[g];
        s += av.x * bv.x + av.y * bv.y + av.z * bv.z + av.w * bv.w;
    }
    for (int e = (n4 << 2) + i; e < n; e += stride) s += a[e] * b[e];
    for (int off = 32; off > 0; off >>= 1) s += __shfl_down(s, off, 64);
    __shared__ float wsum[4];
    int lane = threadIdx.x & 63, wv = threadIdx.x >> 6;
    if (lane == 0) wsum[wv] = s;
    __syncthreads();
    if (threadIdx.x == 0) atomicAdd(acc, wsum[0] + wsum[1] + wsum[2] + wsum[3]);
}

// ============================ launch ============================

static inline size_t align256(size_t x) { return (x + 255) & ~(size_t)255; }

extern "C" void kernel_launch(void* const* d_in, const int* in_sizes, int n_in,
                              void* d_out, int out_size, void* d_ws, size_t ws_size,
                              hipStream_t stream) {
    const float* features = (const float*)d_in[0];   // [N*2]
    const float* norm     = (const float*)d_in[1];   // [E]
    const float* V        = (const float*)d_in[2];   // [L,B,2,2]
    const float* comp     = (const float*)d_in[3];   // [L,R,B]
    const float* bias     = (const float*)d_in[4];   // [L,2]
    const float* w_mlp    = (const float*)d_in[5];   // [N*2]
    const float* b_mlp    = (const float*)d_in[6];   // [1]
    const int*   esrc     = (const int*)d_in[7];
    const int*   edst     = (const int*)d_in[8];
    const int*   etyp     = (const int*)d_in[9];

    int NH = in_sizes[0];
    int N  = NH / 2;
    int E  = in_sizes[7];

    char* ws = (char*)d_ws;
    size_t oW    = 0;                                        // [256] f32
    size_t oAcc  = align256(oW + 1024);
    size_t oOvf  = align256(oAcc + 4);
    size_t oBase = align256(oOvf + 4);
    size_t oTot  = align256(oBase + (size_t)(NB + 1) * 4);
    size_t oFH   = align256(oTot + (size_t)NB * 4);          // half2 features [N]
    size_t oAH   = align256(oFH + (size_t)N * 4);
    size_t oBH   = align256(oAH + (size_t)N * 4);
    size_t oCH   = align256(oBH + (size_t)N * 4);
    size_t oOff  = align256(oCH + (size_t)N * 4);            // u32 [N+1]
    size_t oHist = align256(oOff + (size_t)(N + 1) * 4);     // u32 [SBLK*NB] = 2MB
    size_t oPack = align256(oHist + (size_t)SBLK * NB * 4);  // uint2 [E]
    size_t REQ   = oPack + (size_t)E * 8;                    // ~150MB

    // fallback f32 scratch overlays the sort-path big arrays
    float* A = (float*)(ws + oFH);      // 8MB: spans FH+AH
    float* B = (float*)(ws + oBH);      // 8MB: spans BH+CH
    float* C = (float*)(ws + oPack);    // 8MB: start of pack region

    float* W      = (float*)(ws + oW);
    float* acc    = (float*)(ws + oAcc);
    unsigned* ovfctr = (unsigned*)(ws + oOvf);

    prep_kernel<<<1, 256, 0, stream>>>(V, comp, W, acc, ovfctr);

    if (ws_size >= REQ && N <= (1 << 20)) {
        __half2* FH = (__half2*)(ws + oFH);
        __half2* AH = (__half2*)(ws + oAH);
        __half2* BH = (__half2*)(ws + oBH);
        __half2* CH = (__half2*)(ws + oCH);
        unsigned* base      = (unsigned*)(ws + oBase);
        unsigned* totals    = (unsigned*)(ws + oTot);
        unsigned* offArr    = (unsigned*)(ws + oOff);
        unsigned* blockhist = (unsigned*)(ws + oHist);
        uint2*    packed    = (uint2*)(ws + oPack);
        unsigned long long* packed8 = (unsigned long long*)packed;

        int per = (((E + SBLK - 1) / SBLK) + 3) & ~3;   // multiple of 4
        int nbkt = (N + NBINS - 1) >> BSH;              // buckets actually holding nodes

        static bool attr_done = false;
        if (!attr_done) {
            (void)hipFuncSetAttribute((const void*)subsort_kernel,
                                      hipFuncAttributeMaxDynamicSharedMemorySize,
                                      SUBSORT_LDS_BYTES);
            attr_done = true;
        }

        int cb = min((N + TPB - 1) / TPB, 2048);
        f2h_kernel    <<<cb,   TPB, 0, stream>>>((const float2*)features, FH, N);
        hist_kernel   <<<SBLK, TPB, 0, stream>>>(edst, blockhist, E, per);
        colscan_kernel<<<NB,   TPB, 0, stream>>>(blockhist, totals);
        scan_kernel   <<<1,    TPB, 0, stream>>>(totals, base);
        scatter_kernel<<<SBLK, TPB, 0, stream>>>(esrc, edst, etyp, norm,
                                                 blockhist, base, packed, E, per);
        // blockhist is dead after scatter -> reused as overflow scratch
        subsort_kernel<<<nbkt, TPB, SUBSORT_LDS_BYTES, stream>>>(
            packed8, base, offArr, (unsigned long long*)blockhist, ovfctr, N, E);

        int ngrid = (N + TPB - 1) / TPB;
        const float2* w2 = (const float2*)w_mlp;

        // L0: AH = relu(h0 + b0)
        csr_edge_kernel<<<ngrid, TPB, 0, stream>>>(packed8, offArr, FH, W + 0,
            bias + 0, nullptr, AH, nullptr, acc, N, 1);
        // L1: BH = relu(h1 + b1) + features
        csr_edge_kernel<<<ngrid, TPB, 0, stream>>>(packed8, offArr, AH, W + 64,
            bias + 2, FH, BH, nullptr, acc, N, 1);
        // L2: CH = relu(h2 + b2)
        csr_edge_kernel<<<ngrid, TPB, 0, stream>>>(packed8, offArr, BH, W + 128,
            bias + 4, nullptr, CH, nullptr, acc, N, 1);
        // L3: x4 = (h3 + b3) + B, fused dot with w_mlp (x4 not stored)
        csr_edge_kernel<<<ngrid, TPB, 0, stream>>>(packed8, offArr, CH, W + 192,
            bias + 6, BH, nullptr, w2, acc, N, 0);
    } else {
        // fallback: round-1 atomic path (f32 throughout)
        int zb = (NH / 4 + 255) / 256;
        int eb = (E / 4 + 255) / 256;
        int nb = (N + 255) / 256;
        int db = (NH / 4 + 255) / 256;

        zero_kernel<<<zb, 256, 0, stream>>>((float4*)A, NH / 4);
        edge_kernel<<<eb, 256, 0, stream>>>(features, esrc, edst, etyp, norm, W + 0, A, E);
        node_kernel<<<nb, 256, 0, stream>>>(A, bias + 0, nullptr, A, N, 1);

        zero_kernel<<<zb, 256, 0, stream>>>((float4*)B, NH / 4);
        edge_kernel<<<eb, 256, 0, stream>>>(A, esrc, edst, etyp, norm, W + 64, B, E);
        node_kernel<<<nb, 256, 0, stream>>>(B, bias + 2, features, B, N, 1);

        zero_kernel<<<zb, 256, 0, stream>>>((float4*)C, NH / 4);
        edge_kernel<<<eb, 256, 0, stream>>>(B, esrc, edst, etyp, norm, W + 128, C, E);
        node_kernel<<<nb, 256, 0, stream>>>(C, bias + 4, nullptr, C, N, 1);

        zero_kernel<<<zb, 256, 0, stream>>>((float4*)A, NH / 4);
        edge_kernel<<<eb, 256, 0, stream>>>(C, esrc, edst, etyp, norm, W + 192, A, E);
        node_kernel<<<nb, 256, 0, stream>>>(A, bias + 6, B, A, N, 0);

        dot_kernel<<<db, 256, 0, stream>>>(A, w_mlp, acc, NH);
    }

    finalize_kernel<<<1, 1, 0, stream>>>(acc, b_mlp, (float*)d_out);
}

// Round 5
// 1203.338 us; speedup vs baseline: 5.3525x; 1.6549x over previous
//
#include <hip/hip_runtime.h>
#include <hip/hip_bf16.h>
#include <hip/hip_fp16.h>

#define HD 2
#define LAYERS 4
#define RELS 16
#define BASES 8

#define BSH   10            // 1024 nodes per bucket (bucket fits in LDS for subsort)
#define NB    1024          // dst buckets (bucket = dst >> BSH); N<=2^20
#define NBINS (1 << BSH)    // nodes per bucket
#define SBLK  512           // sort chunk blocks
#define TPB   256
#define CAP   18176         // max staged edges per bucket (mean ~16.4K, +14 sigma)
#define OVFCAP 40960        // overflow slot capacity (edges)
#define LCAP  6144          // per-block staged edges in csr_edge (mean 4096, +32 sigma)

static const int SUBSORT_LDS_BYTES = CAP * 8 + NBINS * 4 + 64;   // ~146 KB

// ============================ common ============================

// W[l][r][i][o] = sum_b comp[l,r,b] * V[l,b,i,o]; zero accumulators.
__global__ void prep_kernel(const float* __restrict__ V, const float* __restrict__ comp,
                            float* __restrict__ W, float* __restrict__ acc,
                            unsigned* __restrict__ ovfctr) {
    int idx = threadIdx.x;            // 0..255 = l*64 + r*4 + io
    if (idx < LAYERS * RELS * 4) {
        int l  = idx >> 6;
        int r  = (idx >> 2) & (RELS - 1);
        int io = idx & 3;
        float s = 0.f;
        for (int b = 0; b < BASES; ++b)
            s += comp[(l * RELS + r) * BASES + b] * V[(l * BASES + b) * 4 + io];
        W[idx] = s;
    }
    if (idx == 0) { *acc = 0.f; *ovfctr = 0u; }
}

__global__ void finalize_kernel(const float* __restrict__ acc,
                                const float* __restrict__ b_mlp,
                                float* __restrict__ out) {
    float v = *acc + b_mlp[0];
    out[0] = 1.f / (1.f + expf(-v));
}

// features f32 -> half2 (4B/node): gather working set 4MB = one XCD L2.
__global__ __launch_bounds__(TPB) void f2h_kernel(const float2* __restrict__ f,
                                                  __half2* __restrict__ h, int N) {
    int i = blockIdx.x * TPB + threadIdx.x;
    int stride = gridDim.x * TPB;
    for (; i < N; i += stride)
        h[i] = __float22half2_rn(f[i]);
}

// ============================ sort path ============================

// S1: per-chunk histogram of dst buckets.  blockhist[blk*NB + bucket]
__global__ __launch_bounds__(TPB) void hist_kernel(const int* __restrict__ dst,
                                                   unsigned* __restrict__ blockhist,
                                                   int E, int per) {
    __shared__ unsigned hist[NB];
    for (int i = threadIdx.x; i < NB; i += TPB) hist[i] = 0u;
    __syncthreads();
    int blk = blockIdx.x;
    int e0 = blk * per;              // multiple of 4
    int e1 = min(e0 + per, E);
    const int4* dst4 = (const int4*)dst;
    int g0 = e0 >> 2, g1 = e1 >> 2;
    for (int g = g0 + threadIdx.x; g < g1; g += TPB) {
        int4 d = dst4[g];
        atomicAdd(&hist[((unsigned)d.x) >> BSH], 1u);
        atomicAdd(&hist[((unsigned)d.y) >> BSH], 1u);
        atomicAdd(&hist[((unsigned)d.z) >> BSH], 1u);
        atomicAdd(&hist[((unsigned)d.w) >> BSH], 1u);
    }
    for (int e = (g1 << 2) + threadIdx.x; e < e1; e += TPB)   // tail (E%4)
        atomicAdd(&hist[((unsigned)dst[e]) >> BSH], 1u);
    __syncthreads();
    for (int i = threadIdx.x; i < NB; i += TPB)
        blockhist[(size_t)blk * NB + i] = hist[i];
}

// S2a: per-bucket column exclusive scan over chunks (in place); totals[bucket] out.
// SBLK/TPB = 2 chunks per thread.
__global__ __launch_bounds__(TPB) void colscan_kernel(unsigned* __restrict__ blockhist,
                                                      unsigned* __restrict__ totals) {
    int bucket = blockIdx.x;
    int t = threadIdx.x;
    unsigned v0 = blockhist[(size_t)(2 * t)     * NB + bucket];
    unsigned v1 = blockhist[(size_t)(2 * t + 1) * NB + bucket];
    unsigned run = v0 + v1;
    __shared__ unsigned s[TPB];
    s[t] = run;
    __syncthreads();
    for (int off = 1; off < TPB; off <<= 1) {
        unsigned x = (t >= off) ? s[t - off] : 0u;
        __syncthreads();
        s[t] += x;
        __syncthreads();
    }
    unsigned base = s[t] - run;
    blockhist[(size_t)(2 * t)     * NB + bucket] = base;
    blockhist[(size_t)(2 * t + 1) * NB + bucket] = base + v0;
    if (t == TPB - 1) totals[bucket] = s[TPB - 1];
}

// S2b: exclusive scan of NB totals -> base[NB+1].  NB/TPB = 4 per thread.
__global__ __launch_bounds__(TPB) void scan_kernel(const unsigned* __restrict__ totals,
                                                   unsigned* __restrict__ base) {
    int t = threadIdx.x;
    unsigned v[4]; unsigned run = 0;
#pragma unroll
    for (int k = 0; k < 4; ++k) { v[k] = run; run += totals[4 * t + k]; }
    __shared__ unsigned s[TPB];
    s[t] = run;
    __syncthreads();
    for (int off = 1; off < TPB; off <<= 1) {
        unsigned x = (t >= off) ? s[t - off] : 0u;
        __syncthreads();
        s[t] += x;
        __syncthreads();
    }
    unsigned b0 = s[t] - run;
#pragma unroll
    for (int k = 0; k < 4; ++k) base[4 * t + k] = b0 + v[k];
    if (t == TPB - 1) base[NB] = s[TPB - 1];
}

// S3: scatter edges into dst-bucket order.
// packed: {src:u32,  doff[0:9] | typ[12:15] | f16(norm)[16:31]}
__global__ __launch_bounds__(TPB) void scatter_kernel(const int* __restrict__ src,
                                                      const int* __restrict__ dst,
                                                      const int* __restrict__ typ,
                                                      const float* __restrict__ norm,
                                                      const unsigned* __restrict__ blockhist,
                                                      const unsigned* __restrict__ base,
                                                      uint2* __restrict__ packed,
                                                      int E, int per) {
    __shared__ unsigned cnt[NB];
    int blk = blockIdx.x;
    for (int i = threadIdx.x; i < NB; i += TPB)
        cnt[i] = blockhist[(size_t)blk * NB + i] + base[i];
    __syncthreads();
    int e0 = blk * per;
    int e1 = min(e0 + per, E);
    const int4*   src4 = (const int4*)src;
    const int4*   dst4 = (const int4*)dst;
    const int4*   typ4 = (const int4*)typ;
    const float4* nrm4 = (const float4*)norm;
    int g0 = e0 >> 2, g1 = e1 >> 2;

#define PUT(SS, DD, TT, NN)                                                       \
    {                                                                             \
        unsigned _d = (unsigned)(DD);                                             \
        unsigned _bucket = _d >> BSH;                                             \
        unsigned _pos = atomicAdd(&cnt[_bucket], 1u);                             \
        unsigned _w1 = (_d & ((1u << BSH) - 1u)) | (((unsigned)(TT)) << 12) |     \
                       ((unsigned)__half_as_ushort(__float2half_rn(NN)) << 16);   \
        packed[_pos] = make_uint2((unsigned)(SS), _w1);                           \
    }

    for (int g = g0 + threadIdx.x; g < g1; g += TPB) {
        int4 s = src4[g];
        int4 d = dst4[g];
        int4 t = typ4[g];
        float4 nm = nrm4[g];
        PUT(s.x, d.x, t.x, nm.x)
        PUT(s.y, d.y, t.y, nm.y)
        PUT(s.z, d.z, t.z, nm.z)
        PUT(s.w, d.w, t.w, nm.w)
    }
    for (int e = (g1 << 2) + threadIdx.x; e < e1; e += TPB)   // tail (E%4)
        PUT(src[e], dst[e], typ[e], norm[e])
#undef PUT
}

// S4: IN-PLACE within-bucket counting sort -> exact dst order + CSR offsets.
// One block per bucket; bucket staged in 146KB dynamic LDS, scattered back
// into the same packed[] range in exact dst order. Overflow (> CAP, +14 sigma)
// stages via a global scratch slot.
__global__ __launch_bounds__(TPB) void subsort_kernel(
    unsigned long long* __restrict__ packed8,     // sorted in place
    const unsigned* __restrict__ base,
    unsigned* __restrict__ off,                   // [N+1]
    unsigned long long* __restrict__ ovfbuf,      // 2MB scratch (dead blockhist)
    unsigned* __restrict__ ovfctr,
    int N, int E)
{
    extern __shared__ unsigned long long smem[];
    unsigned long long* stage = smem;                       // CAP entries
    unsigned* hist  = (unsigned*)(smem + CAP);              // NBINS counts->cursors
    unsigned* wpart = hist + NBINS;                         // per-wave scan partials

    int b = blockIdx.x;
    int t = threadIdx.x;
    unsigned e0 = base[b], e1 = base[b + 1];
    unsigned len = e1 - e0;

    __shared__ unsigned long long* gs;
    if (len > CAP) {                  // statistical impossibility; safe anyway
        if (t == 0) {
            unsigned slot = atomicAdd(ovfctr, 1u) % 6u;
            gs = ovfbuf + (size_t)slot * OVFCAP;
        }
        __syncthreads();
        stage = gs;
    }

    for (int i = t; i < NBINS; i += TPB) hist[i] = 0u;
    __syncthreads();

    // pass 1: stage bucket + per-node histogram
    for (unsigned i = t; i < len; i += TPB) {
        unsigned long long q = packed8[e0 + i];
        stage[i] = q;
        atomicAdd(&hist[(unsigned)(q >> 32) & (NBINS - 1u)], 1u);
    }
    __syncthreads();

    // exclusive scan of NBINS bins: 4 serial bins/thread + wave/block scan
    unsigned loc[4]; unsigned run = 0;
#pragma unroll
    for (int k = 0; k < 4; ++k) { loc[k] = run; run += hist[t * 4 + k]; }

    unsigned lane = t & 63, wv = t >> 6;
    unsigned v = run;
    for (int o = 1; o < 64; o <<= 1) {
        unsigned u = __shfl_up(v, o, 64);
        if (lane >= (unsigned)o) v += u;
    }
    if (lane == 63) wpart[wv] = v;
    __syncthreads();                 // also: all hist reads done
    unsigned wbase = 0;
    for (int w = 0; w < (int)(TPB / 64); ++w) if ((unsigned)w < wv) wbase += wpart[w];
    unsigned excl = wbase + v - run; // exclusive prefix of this thread's 1st bin

    unsigned nodeBase = (unsigned)b << BSH;
#pragma unroll
    for (int k = 0; k < 4; ++k) {
        unsigned bin = (unsigned)(t * 4 + k);
        unsigned pos = e0 + excl + loc[k];
        hist[bin] = pos;             // global cursor for this node's segment
        unsigned node = nodeBase + bin;
        if (node < (unsigned)N) off[node] = pos;
    }
    if (b == 0 && t == 0) off[N] = (unsigned)E;
    __syncthreads();

    // pass 2: scatter back into exact dst order (within own [e0,e1) range)
    for (unsigned i = t; i < len; i += TPB) {
        unsigned long long q = stage[i];
        unsigned bin = (unsigned)(q >> 32) & (NBINS - 1u);
        unsigned pos = atomicAdd(&hist[bin], 1u);
        packed8[pos] = q;
    }
}

// Per-layer edge pass over CSR: block stages its contiguous ~4096-edge window
// in LDS (coalesced, non-temporal -> L2 stays free for the x gather), then one
// thread per dst node walks its segment OUT OF LDS. SoA + XOR swizzle
// (i ^ ((i>>4)&15)) keeps the stride-16-dword reads ~conflict-free.
// Zero atomics; fused epilogue.
__global__ __launch_bounds__(TPB) void csr_edge_kernel(
    const unsigned long long* __restrict__ rec8,  // packed, exact dst order
    const unsigned* __restrict__ off,             // [N+1]
    const __half2* __restrict__ xh,               // gather source [N], 4MB
    const float* __restrict__ Wl,                 // [64] this layer
    const float* __restrict__ bias2,              // [2]
    const __half2* __restrict__ skiph,            // nullable
    __half2* __restrict__ outh,                   // nullable
    const float2* __restrict__ w2,                // nullable (w_mlp as float2[N])
    float* __restrict__ acc,                      // dot accumulator
    int N, int do_relu)
{
    __shared__ float sW[64];
    __shared__ float wred[TPB / 64];
    __shared__ unsigned slo[LCAP];
    __shared__ unsigned shi[LCAP];
    int t = threadIdx.x;
    if (t < 64) sW[t] = Wl[t];

    int d0   = blockIdx.x * TPB;
    int dmax = min(d0 + TPB, N);
    unsigned e0 = off[d0];
    unsigned eE = off[dmax];
    unsigned len = eE - e0;
    bool useLds = (len <= (unsigned)LCAP);   // block-uniform

    if (useLds) {
        for (unsigned i = t; i < len; i += TPB) {
            unsigned long long q = __builtin_nontemporal_load(&rec8[e0 + i]);
            unsigned sw = i ^ ((i >> 4) & 15u);
            slo[sw] = (unsigned)q;
            shi[sw] = (unsigned)(q >> 32);
        }
    }
    __syncthreads();

    int d = d0 + t;
    float r0 = 0.f, r1 = 0.f;
    if (d < N) {
        unsigned ea = off[d], eb = off[d + 1];
        if (useLds) {
            for (unsigned e = ea - e0; e < eb - e0; ++e) {
                unsigned sw = e ^ ((e >> 4) & 15u);
                unsigned s = slo[sw];
                unsigned m = shi[sw];
                __half2 hv = xh[s];
                float x0 = __low2float(hv), x1 = __high2float(hv);
                int wb = (int)((m >> 12) & 15u) << 2;
                float nm = __half2float(__ushort_as_half((unsigned short)(m >> 16)));
                r0 += (x0 * sW[wb + 0] + x1 * sW[wb + 2]) * nm;
                r1 += (x0 * sW[wb + 1] + x1 * sW[wb + 3]) * nm;
            }
        } else {
            for (unsigned e = ea; e < eb; ++e) {
                unsigned long long q = __builtin_nontemporal_load(&rec8[e]);
                unsigned m = (unsigned)(q >> 32);
                __half2 hv = xh[(unsigned)q];
                float x0 = __low2float(hv), x1 = __high2float(hv);
                int wb = (int)((m >> 12) & 15u) << 2;
                float nm = __half2float(__ushort_as_half((unsigned short)(m >> 16)));
                r0 += (x0 * sW[wb + 0] + x1 * sW[wb + 2]) * nm;
                r1 += (x0 * sW[wb + 1] + x1 * sW[wb + 3]) * nm;
            }
        }
        r0 += bias2[0]; r1 += bias2[1];
        if (do_relu) { r0 = fmaxf(r0, 0.f); r1 = fmaxf(r1, 0.f); }
        if (skiph) { __half2 sv = skiph[d]; r0 += __low2float(sv); r1 += __high2float(sv); }
        if (outh) outh[d] = __float22half2_rn(make_float2(r0, r1));
    }
    if (w2) {
        float part = 0.f;
        if (d < N) { float2 wv = w2[d]; part = r0 * wv.x + r1 * wv.y; }
        for (int o = 32; o > 0; o >>= 1) part += __shfl_down(part, o, 64);
        if ((t & 63) == 0) wred[t >> 6] = part;
        __syncthreads();
        if (t == 0) {
            float s = 0.f;
            for (int w = 0; w < (int)(TPB / 64); ++w) s += wred[w];
            atomicAdd(acc, s);
        }
    }
}

// ============================ fallback path (round-1, known-good) ============================

__global__ void zero_kernel(float4* __restrict__ p, int n4) {
    int i = blockIdx.x * blockDim.x + threadIdx.x;
    int stride = gridDim.x * blockDim.x;
    for (; i < n4; i += stride) p[i] = make_float4(0.f, 0.f, 0.f, 0.f);
}

__global__ __launch_bounds__(256) void edge_kernel(
    const float* __restrict__ x, const int* __restrict__ src,
    const int* __restrict__ dst, const int* __restrict__ typ,
    const float* __restrict__ norm, const float* __restrict__ Wl,
    float* __restrict__ h, int E)
{
    __shared__ float sW[64];
    if (threadIdx.x < 64) sW[threadIdx.x] = Wl[threadIdx.x];
    __syncthreads();
    const float2* __restrict__ x2 = (const float2*)x;
    int tid = blockIdx.x * blockDim.x + threadIdx.x;
    int stride = gridDim.x * blockDim.x;
    for (int e = tid; e < E; e += stride) {
        int s = src[e], d = dst[e], t = typ[e];
        float nm = norm[e];
        float2 xv = x2[s];
        int wb = t << 2;
        float m0 = (xv.x * sW[wb + 0] + xv.y * sW[wb + 2]) * nm;
        float m1 = (xv.x * sW[wb + 1] + xv.y * sW[wb + 3]) * nm;
        atomicAdd(&h[2 * (size_t)d],     m0);
        atomicAdd(&h[2 * (size_t)d + 1], m1);
    }
}

__global__ void node_kernel(const float* __restrict__ h, const float* __restrict__ bias_l,
                            const float* __restrict__ skip, float* __restrict__ xout,
                            int N, int do_relu)
{
    float b0 = bias_l[0], b1 = bias_l[1];
    const float2* __restrict__ h2 = (const float2*)h;
    const float2* __restrict__ s2 = (const float2*)skip;
    float2* __restrict__ o2 = (float2*)xout;
    int i = blockIdx.x * blockDim.x + threadIdx.x;
    int stride = gridDim.x * blockDim.x;
    for (; i < N; i += stride) {
        float2 v = h2[i];
        v.x += b0; v.y += b1;
        if (do_relu) { v.x = fmaxf(v.x, 0.f); v.y = fmaxf(v.y, 0.f); }
        if (skip) { float2 sv = s2[i]; v.x += sv.x; v.y += sv.y; }
        o2[i] = v;
    }
}

__global__ __launch_bounds__(256) void dot_kernel(const float* __restrict__ a,
                                                  const float* __restrict__ b,
                                                  float* __restrict__ acc, int n)
{
    int i = blockIdx.x * blockDim.x + threadIdx.x;
    int stride = gridDim.x * blockDim.x;
    float s = 0.f;
    int n4 = n >> 2;
    const float4* __restrict__ a4 = (const float4*)a;
    const float4* __restrict__ b4 = (const float4*)b;
    for (int g = i; g < n4; g += stride) {
        float4 av = a4[g], bv = b4[g];
        s += av.x * bv.x + av.y * bv.y + av.z * bv.z + av.w * bv.w;
    }
    for (int e = (n4 << 2) + i; e < n; e += stride) s += a[e] * b[e];
    for (int off = 32; off > 0; off >>= 1) s += __shfl_down(s, off, 64);
    __shared__ float wsum[4];
    int lane = threadIdx.x & 63, wv = threadIdx.x >> 6;
    if (lane == 0) wsum[wv] = s;
    __syncthreads();
    if (threadIdx.x == 0) atomicAdd(acc, wsum[0] + wsum[1] + wsum[2] + wsum[3]);
}

// ============================ launch ============================

static inline size_t align256(size_t x) { return (x + 255) & ~(size_t)255; }

extern "C" void kernel_launch(void* const* d_in, const int* in_sizes, int n_in,
                              void* d_out, int out_size, void* d_ws, size_t ws_size,
                              hipStream_t stream) {
    const float* features = (const float*)d_in[0];   // [N*2]
    const float* norm     = (const float*)d_in[1];   // [E]
    const float* V        = (const float*)d_in[2];   // [L,B,2,2]
    const float* comp     = (const float*)d_in[3];   // [L,R,B]
    const float* bias     = (const float*)d_in[4];   // [L,2]
    const float* w_mlp    = (const float*)d_in[5];   // [N*2]
    const float* b_mlp    = (const float*)d_in[6];   // [1]
    const int*   esrc     = (const int*)d_in[7];
    const int*   edst     = (const int*)d_in[8];
    const int*   etyp     = (const int*)d_in[9];

    int NH = in_sizes[0];
    int N  = NH / 2;
    int E  = in_sizes[7];

    char* ws = (char*)d_ws;
    size_t oW    = 0;                                        // [256] f32
    size_t oAcc  = align256(oW + 1024);
    size_t oOvf  = align256(oAcc + 4);
    size_t oBase = align256(oOvf + 4);
    size_t oTot  = align256(oBase + (size_t)(NB + 1) * 4);
    size_t oFH   = align256(oTot + (size_t)NB * 4);          // half2 features [N]
    size_t oAH   = align256(oFH + (size_t)N * 4);
    size_t oBH   = align256(oAH + (size_t)N * 4);
    size_t oCH   = align256(oBH + (size_t)N * 4);
    size_t oOff  = align256(oCH + (size_t)N * 4);            // u32 [N+1]
    size_t oHist = align256(oOff + (size_t)(N + 1) * 4);     // u32 [SBLK*NB] = 2MB
    size_t oPack = align256(oHist + (size_t)SBLK * NB * 4);  // uint2 [E]
    size_t REQ   = oPack + (size_t)E * 8;                    // ~150MB

    // fallback f32 scratch overlays the sort-path big arrays
    float* A = (float*)(ws + oFH);      // 8MB: spans FH+AH
    float* B = (float*)(ws + oBH);      // 8MB: spans BH+CH
    float* C = (float*)(ws + oPack);    // 8MB: start of pack region

    float* W      = (float*)(ws + oW);
    float* acc    = (float*)(ws + oAcc);
    unsigned* ovfctr = (unsigned*)(ws + oOvf);

    prep_kernel<<<1, 256, 0, stream>>>(V, comp, W, acc, ovfctr);

    if (ws_size >= REQ && N <= (1 << 20)) {
        __half2* FH = (__half2*)(ws + oFH);
        __half2* AH = (__half2*)(ws + oAH);
        __half2* BH = (__half2*)(ws + oBH);
        __half2* CH = (__half2*)(ws + oCH);
        unsigned* base      = (unsigned*)(ws + oBase);
        unsigned* totals    = (unsigned*)(ws + oTot);
        unsigned* offArr    = (unsigned*)(ws + oOff);
        unsigned* blockhist = (unsigned*)(ws + oHist);
        uint2*    packed    = (uint2*)(ws + oPack);
        unsigned long long* packed8 = (unsigned long long*)packed;

        int per = (((E + SBLK - 1) / SBLK) + 3) & ~3;   // multiple of 4
        int nbkt = (N + NBINS - 1) >> BSH;              // buckets actually holding nodes

        static bool attr_done = false;
        if (!attr_done) {
            (void)hipFuncSetAttribute((const void*)subsort_kernel,
                                      hipFuncAttributeMaxDynamicSharedMemorySize,
                                      SUBSORT_LDS_BYTES);
            attr_done = true;
        }

        int cb = min((N + TPB - 1) / TPB, 2048);
        f2h_kernel    <<<cb,   TPB, 0, stream>>>((const float2*)features, FH, N);
        hist_kernel   <<<SBLK, TPB, 0, stream>>>(edst, blockhist, E, per);
        colscan_kernel<<<NB,   TPB, 0, stream>>>(blockhist, totals);
        scan_kernel   <<<1,    TPB, 0, stream>>>(totals, base);
        scatter_kernel<<<SBLK, TPB, 0, stream>>>(esrc, edst, etyp, norm,
                                                 blockhist, base, packed, E, per);
        // blockhist is dead after scatter -> reused as overflow scratch
        subsort_kernel<<<nbkt, TPB, SUBSORT_LDS_BYTES, stream>>>(
            packed8, base, offArr, (unsigned long long*)blockhist, ovfctr, N, E);

        int ngrid = (N + TPB - 1) / TPB;
        const float2* w2 = (const float2*)w_mlp;

        // L0: AH = relu(h0 + b0)
        csr_edge_kernel<<<ngrid, TPB, 0, stream>>>(packed8, offArr, FH, W + 0,
            bias + 0, nullptr, AH, nullptr, acc, N, 1);
        // L1: BH = relu(h1 + b1) + features
        csr_edge_kernel<<<ngrid, TPB, 0, stream>>>(packed8, offArr, AH, W + 64,
            bias + 2, FH, BH, nullptr, acc, N, 1);
        // L2: CH = relu(h2 + b2)
        csr_edge_kernel<<<ngrid, TPB, 0, stream>>>(packed8, offArr, BH, W + 128,
            bias + 4, nullptr, CH, nullptr, acc, N, 1);
        // L3: x4 = (h3 + b3) + B, fused dot with w_mlp (x4 not stored)
        csr_edge_kernel<<<ngrid, TPB, 0, stream>>>(packed8, offArr, CH, W + 192,
            bias + 6, BH, nullptr, w2, acc, N, 0);
    } else {
        // fallback: round-1 atomic path (f32 throughout)
        int zb = (NH / 4 + 255) / 256;
        int eb = (E / 4 + 255) / 256;
        int nb = (N + 255) / 256;
        int db = (NH / 4 + 255) / 256;

        zero_kernel<<<zb, 256, 0, stream>>>((float4*)A, NH / 4);
        edge_kernel<<<eb, 256, 0, stream>>>(features, esrc, edst, etyp, norm, W + 0, A, E);
        node_kernel<<<nb, 256, 0, stream>>>(A, bias + 0, nullptr, A, N, 1);

        zero_kernel<<<zb, 256, 0, stream>>>((float4*)B, NH / 4);
        edge_kernel<<<eb, 256, 0, stream>>>(A, esrc, edst, etyp, norm, W + 64, B, E);
        node_kernel<<<nb, 256, 0, stream>>>(B, bias + 2, features, B, N, 1);

        zero_kernel<<<zb, 256, 0, stream>>>((float4*)C, NH / 4);
        edge_kernel<<<eb, 256, 0, stream>>>(B, esrc, edst, etyp, norm, W + 128, C, E);
        node_kernel<<<nb, 256, 0, stream>>>(C, bias + 4, nullptr, C, N, 1);

        zero_kernel<<<zb, 256, 0, stream>>>((float4*)A, NH / 4);
        edge_kernel<<<eb, 256, 0, stream>>>(C, esrc, edst, etyp, norm, W + 192, A, E);
        node_kernel<<<nb, 256, 0, stream>>>(A, bias + 6, B, A, N, 0);

        dot_kernel<<<db, 256, 0, stream>>>(A, w_mlp, acc, NH);
    }

    finalize_kernel<<<1, 1, 0, stream>>>(acc, b_mlp, (float*)d_out);
}